// Round 1
// baseline (86.425 us; speedup 1.0000x reference)
//
#include <hip/hip_runtime.h>

#define NDIM 31
#define NPIX (256 * 256)
#define CG_FULL 3           // full CG iterations
                            // + 1 final partial iteration (phi term only)

__device__ __forceinline__ float rcpf(float x) { return __builtin_amdgcn_rcpf(x); }

// DPP-shuffled copy (VALU pipe). 0xB1=xor1, 0x4E=xor2, 0x1B=quad reverse(xor3),
// 0x141=row_half_mirror(xor7 in 8), 0x124=row_ror:4, 0x128=row_ror:8(=xor8 in 16)
template <int CTRL>
__device__ __forceinline__ float dppf(float v) {
    return __int_as_float(__builtin_amdgcn_update_dpp(
        0, __float_as_int(v), CTRL, 0xF, 0xF, true));
}
__device__ __forceinline__ float xor4f(float v) { return dppf<0x1B>(dppf<0x141>(v)); }

#if __has_builtin(__builtin_amdgcn_permlane16_swap)
#define HAVE_PL16 1
typedef unsigned int uint2v __attribute__((ext_vector_type(2)));
#else
#define HAVE_PL16 0
// fallback: xor16 within each 32-lane group (DS pipe)
__device__ __forceinline__ float swz16(float v) {
    return __int_as_float(__builtin_amdgcn_ds_swizzle(__float_as_int(v), 0x401F));
}
#endif

// final cross-16 WHT stage: s16*v[l] + v[l^16]  (pure VALU on gfx950)
__device__ __forceinline__ float whtfin(float v, float s16) {
#if HAVE_PL16
    // v_permlane16_swap_b32: first operand keeps EVEN rows, second keeps ODD rows.
    // r[0][l] = (l&16) ? v[l^16] : v[l];  r[1][l] = (l&16) ? v[l] : v[l^16]
    uint2v r = __builtin_amdgcn_permlane16_swap(
        __float_as_uint(v), __float_as_uint(v), false, false);
    // even row (s16=+1): r0+r1 = v[l]+v[l^16]; odd row (s16=-1): r0-r1 = v[l^16]-v[l]
    return fmaf(s16, __uint_as_float(r[1]), __uint_as_float(r[0]));
#else
    return fmaf(s16, v, swz16(v));
#endif
}

// v[l] + v[l^16] (orientation-independent)
__device__ __forceinline__ float pairsum16(float v) {
#if HAVE_PL16
    uint2v r = __builtin_amdgcn_permlane16_swap(
        __float_as_uint(v), __float_as_uint(v), false, false);
    return __uint_as_float(r[0]) + __uint_as_float(r[1]);
#else
    return v + swz16(v);
#endif
}

struct Sgn { float s1, s2, s4, s8, s16; };

// S-matrix product via WHT: out[l] = (S v)[l-1] for l>=1; out[0] = 0.
// out = 0.5*(sum32(v) - WHT32(v)[l]).  H column 0 is all-ones, so the
// result is independent of the lane-0 pad value (no masking needed).
// The plain-sum chain runs in PARALLEL with the signed butterfly — it
// replaces the old lane-0 ds_bpermute broadcast (WHT[0] == total sum)
// without adding serial latency.
__device__ __forceinline__ float smat(float v, const Sgn& g) {
    // signed butterfly, 4 in-row stages (DPP, VALU)
    float h = fmaf(g.s1, v, dppf<0xB1>(v));
    h = fmaf(g.s2, h, dppf<0x4E>(h));
    h = fmaf(g.s4, h, xor4f(h));
    h = fmaf(g.s8, h, dppf<0x128>(h));
    float hf = whtfin(h, g.s16);          // full WHT32 at every lane
    // plain sum, independent chain (rotations legal for sums)
    float s = v + dppf<0xB1>(v);
    s += dppf<0x4E>(s);
    s += dppf<0x124>(s);
    s += dppf<0x128>(s);
    float T = pairsum16(s);               // total sum, all lanes
    return 0.5f * (T - hf);
}

// sum over each 32-lane half, result in every lane
__device__ __forceinline__ float sum32(float s) {
    s += dppf<0xB1>(s);    // xor1
    s += dppf<0x4E>(s);    // xor2
    s += dppf<0x124>(s);   // ror4 within 16
    s += dppf<0x128>(s);   // ror8 within 16
    return pairsum16(s);   // cross-16
}

__global__ __launch_bounds__(256) void solver_kernel(
    const float* __restrict__ xg, const float* __restrict__ kg,
    const float* __restrict__ tg, float* __restrict__ out)
{
    const int tid = blockIdx.x * 256 + threadIdx.x;
    const int pix = tid >> 5;                 // one 32-lane half per pixel
    const int l = threadIdx.x & 31;           // element = l-1; lane0 = WHT pad

    const float t = tg[0];

    float x = 1.0f, k = 0.0f;
    if (l >= 1) {
        const int base = pix * NDIM + (l - 1);
        x = xg[base];
        k = kg[base];
    }

    Sgn g;
    g.s1  = (l & 1)  ? -1.0f : 1.0f;
    g.s2  = (l & 2)  ? -1.0f : 1.0f;
    g.s4  = (l & 4)  ? -1.0f : 1.0f;
    g.s8  = (l & 8)  ? -1.0f : 1.0f;
    g.s16 = (l & 16) ? -1.0f : 1.0f;

    // rate = S x  (lane-0 pad irrelevant: column 0 of S' is zero)
    float rate = smat(x, g);
    float inv_rate = (l == 0) ? 0.0f : rcpf(rate);

    // v: J = -(S^T v) - 1/x ;  w: Hessian weights (lane0 -> 0 via inv_rate)
    float v = t * (k * inv_rate - 1.0f) + inv_rate;
    float w = (t * k + 1.0f) * inv_rate * inv_rate;

    float invx = rcpf(x);
    float invx2 = invx * invx;

    // b = J (zero at lane 0)
    float b = -smat(v, g) - invx;
    if (l == 0) b = 0.0f;

    // Jacobi diag: diag(H) = (S^T w) + 1/x^2  (S binary => S_ai^2 = S_ai)
    float dH = smat(w, g) + invx2;
    float Minv = (l == 0) ? 0.0f : rcpf(dH);  // keeps lane0 state = 0

    // ---- PCG on H y = b; phi = b^T y accumulated as sum alpha_i * (r_i.z_i)
    float r = b;
    float z = Minv * r;
    float p = z;
    float rz = sum32(r * z);
    float phi = 0.0f;

#pragma unroll
    for (int it = 0; it < CG_FULL; ++it) {
        // Ap = S^T ( w * (S p) ) + invx2 * p   (lane0 stays 0 automatically)
        float q = w * smat(p, g);
        float Ap = fmaf(invx2, p, smat(q, g));

        float pAp = sum32(p * Ap);
        float alpha = rz * rcpf(fmaxf(pAp, 1e-30f)); // clamp: no inf -> no NaN
        phi = fmaf(alpha, rz, phi);
        r = fmaf(-alpha, Ap, r);
        z = Minv * r;
        float rzn = sum32(r * z);
        float beta = rzn * rcpf(fmaxf(rz, 1e-30f));
        rz = rzn;
        p = fmaf(beta, p, z);
    }
    {   // final partial iteration: only the phi increment is observable
        float q = w * smat(p, g);
        float Ap = fmaf(invx2, p, smat(q, g));
        float pAp = sum32(p * Ap);
        float alpha = rz * rcpf(fmaxf(pAp, 1e-30f));
        phi = fmaf(alpha, rz, phi);
    }

    if (l == 0) out[pix] = phi;
}

extern "C" void kernel_launch(void* const* d_in, const int* in_sizes, int n_in,
                              void* d_out, int out_size, void* d_ws, size_t ws_size,
                              hipStream_t stream) {
    const float* xg = (const float*)d_in[0];  // time_points
    const float* kg = (const float*)d_in[1];  // pixels
    // d_in[2] = S — Sylvester S-matrix, structure known analytically, unused
    const float* tg = (const float*)d_in[3];  // t scalar
    float* out = (float*)d_out;

    const int threads = 256;                  // 4 waves = 8 pixels per block
    const int blocks = (NPIX * 32) / threads; // 8192
    solver_kernel<<<blocks, threads, 0, stream>>>(xg, kg, tg, out);
}

// Round 2
// 79.124 us; speedup vs baseline: 1.0923x; 1.0923x over previous
//
#include <hip/hip_runtime.h>

#define NDIM 31
#define NPIX (256 * 256)
#define CG_FULL 3           // full CG iterations
                            // + 1 final partial iteration (phi term only)

__device__ __forceinline__ float rcpf(float x) { return __builtin_amdgcn_rcpf(x); }

// DPP-shuffled copy (VALU pipe). 0xB1=xor1, 0x4E=xor2, 0x124=row_ror:4,
// 0x128=row_ror:8 (== xor8 within a 16-ring)
template <int CTRL>
__device__ __forceinline__ float dppf(float v) {
    return __int_as_float(__builtin_amdgcn_update_dpp(
        0, __float_as_int(v), CTRL, 0xF, 0xF, true));
}
// DS-pipe lane xors within each 32-lane group (issue on LDS pipe, not VALU).
// BitMode offset = (xor<<10) | (or<<5) | and
__device__ __forceinline__ float swz4(float v) {   // lane ^= 4
    return __int_as_float(__builtin_amdgcn_ds_swizzle(__float_as_int(v), 0x101F));
}
__device__ __forceinline__ float swz16(float v) {  // lane ^= 16
    return __int_as_float(__builtin_amdgcn_ds_swizzle(__float_as_int(v), 0x401F));
}
// broadcast lane 0 of each 32-lane half (bbase = half-base byte address)
__device__ __forceinline__ float bperm0(float v, int bbase) {
    return __int_as_float(__builtin_amdgcn_ds_bpermute(bbase, __float_as_int(v)));
}

struct Sgn { float s1, s2, s4, s8, s16; };

// signed 32-point WHT; sign-FMA form v' = s_m*v + v[l^m], 2 issue-ops/stage,
// balanced across VALU (DPP) and DS (swizzle) pipes
__device__ __forceinline__ float wht32(float v, const Sgn& g) {
    v = fmaf(g.s1,  v, dppf<0xB1>(v));   // xor1  (VALU)
    v = fmaf(g.s2,  v, dppf<0x4E>(v));   // xor2  (VALU)
    v = fmaf(g.s4,  v, swz4(v));         // xor4  (DS)
    v = fmaf(g.s8,  v, dppf<0x128>(v));  // xor8  (VALU)
    v = fmaf(g.s16, v, swz16(v));        // xor16 (DS)
    return v;
}

// sum over each 32-lane half, result in every lane (rotations legal for sums)
__device__ __forceinline__ float sum32(float s) {
    s += dppf<0xB1>(s);    // xor1
    s += dppf<0x4E>(s);    // xor2
    s += dppf<0x124>(s);   // ror4 within 16
    s += dppf<0x128>(s);   // ror8 within 16
    s += swz16(s);         // xor16 (DS)
    return s;
}

__global__ __launch_bounds__(256, 8) void solver_kernel(
    const float* __restrict__ xg, const float* __restrict__ kg,
    const float* __restrict__ tg, float* __restrict__ out)
{
    const int tid = blockIdx.x * 256 + threadIdx.x;
    const int pix = tid >> 5;                 // one 32-lane half per pixel
    const int lane = threadIdx.x & 63;
    const int l = lane & 31;                  // element = l-1; lane0 = WHT pad
    const int bbase = (lane & 32) << 2;

    const float t = tg[0];

    float x = 1.0f, k = 0.0f;
    if (l >= 1) {
        const int base = pix * NDIM + (l - 1);
        x = xg[base];
        k = kg[base];
    }

    Sgn g;
    g.s1  = (l & 1)  ? -1.0f : 1.0f;
    g.s2  = (l & 2)  ? -1.0f : 1.0f;
    g.s4  = (l & 4)  ? -1.0f : 1.0f;
    g.s8  = (l & 8)  ? -1.0f : 1.0f;
    g.s16 = (l & 16) ? -1.0f : 1.0f;

    // rate = S x: rate[l] = 0.5*(T - WHT(x)[l]); the lane-0 pad value cancels
    // algebraically (coefficient (1-1)/2 = 0), so no input masking is needed.
    float xh = wht32(x, g);
    float xh0 = bperm0(xh, bbase);            // T = WHT[0], broadcast (DS)
    float rate = 0.5f * (xh0 - xh);
    float inv_rate = (l == 0) ? 0.0f : rcpf(rate);

    // v: J = -(S^T v) - 1/x ;  w: Hessian weights (lane0 -> 0 via inv_rate)
    float v = t * (k * inv_rate - 1.0f) + inv_rate;   // lane0 = -t, cancels in S
    float w = (t * k + 1.0f) * inv_rate * inv_rate;

    float invx = rcpf(x);
    float invx2 = invx * invx;

    // b = J (zero at lane 0)
    float vh = wht32(v, g);
    float vh0 = bperm0(vh, bbase);
    float b = -0.5f * (vh0 - vh) - invx;
    if (l == 0) b = 0.0f;

    // Jacobi diag: diag(H) = (S^T w) + 1/x^2  (S binary => S_ai^2 = S_ai)
    float wh = wht32(w, g);
    float wh0 = bperm0(wh, bbase);
    float dH = 0.5f * (wh0 - wh) + invx2;
    float Minv = (l == 0) ? 0.0f : rcpf(dH);  // keeps lane0 state = 0

    const float w4 = 0.25f * w;   // folds both 0.5 transform scales into one mul

    // ---- PCG on H y = b; phi = b^T y accumulated as sum alpha_i * (r_i.z_i)
    float r = b;
    float z = Minv * r;
    float p = z;
    float rz = sum32(r * z);
    float phi = 0.0f;

#pragma unroll
    for (int it = 0; it < CG_FULL; ++it) {
        // Ap = S^T ( w * (S p) ) + invx2 * p   (lane0 stays 0 automatically)
        float ph = wht32(p, g);
        float ph0 = bperm0(ph, bbase);
        float q = w4 * (ph0 - ph);
        float qh = wht32(q, g);
        float qh0 = bperm0(qh, bbase);
        float Ap = fmaf(invx2, p, qh0 - qh);

        float pAp = sum32(p * Ap);
        float alpha = rz * rcpf(fmaxf(pAp, 1e-30f)); // clamp: no inf -> no NaN
        phi = fmaf(alpha, rz, phi);
        r = fmaf(-alpha, Ap, r);
        z = Minv * r;
        float rzn = sum32(r * z);
        float beta = rzn * rcpf(fmaxf(rz, 1e-30f));
        rz = rzn;
        p = fmaf(beta, p, z);
    }
    {   // final partial iteration: only the phi increment is observable
        float ph = wht32(p, g);
        float ph0 = bperm0(ph, bbase);
        float q = w4 * (ph0 - ph);
        float qh = wht32(q, g);
        float qh0 = bperm0(qh, bbase);
        float Ap = fmaf(invx2, p, qh0 - qh);
        float pAp = sum32(p * Ap);
        float alpha = rz * rcpf(fmaxf(pAp, 1e-30f));
        phi = fmaf(alpha, rz, phi);
    }

    if (l == 0) out[pix] = phi;
}

extern "C" void kernel_launch(void* const* d_in, const int* in_sizes, int n_in,
                              void* d_out, int out_size, void* d_ws, size_t ws_size,
                              hipStream_t stream) {
    const float* xg = (const float*)d_in[0];  // time_points
    const float* kg = (const float*)d_in[1];  // pixels
    // d_in[2] = S — Sylvester S-matrix, structure known analytically, unused
    const float* tg = (const float*)d_in[3];  // t scalar
    float* out = (float*)d_out;

    const int threads = 256;                  // 4 waves = 8 pixels per block
    const int blocks = (NPIX * 32) / threads; // 8192
    solver_kernel<<<blocks, threads, 0, stream>>>(xg, kg, tg, out);
}

// Round 3
// 78.826 us; speedup vs baseline: 1.0964x; 1.0038x over previous
//
#include <hip/hip_runtime.h>

#define NDIM 31
#define NPIX (256 * 256)
#define CG_FULL 3           // full CG iterations
                            // + 1 final partial iteration (phi term only)
#define ILP 2               // independent pixels per 32-lane half

__device__ __forceinline__ float rcpf(float x) { return __builtin_amdgcn_rcpf(x); }

// DPP-shuffled copy (VALU pipe). 0xB1=xor1, 0x4E=xor2, 0x124=row_ror:4,
// 0x128=row_ror:8 (== xor8 within a 16-ring)
template <int CTRL>
__device__ __forceinline__ float dppf(float v) {
    return __int_as_float(__builtin_amdgcn_update_dpp(
        0, __float_as_int(v), CTRL, 0xF, 0xF, true));
}
// DS-pipe lane xors within each 32-lane group (issue on LDS pipe, not VALU).
// BitMode offset = (xor<<10) | (or<<5) | and
__device__ __forceinline__ float swz4(float v) {   // lane ^= 4
    return __int_as_float(__builtin_amdgcn_ds_swizzle(__float_as_int(v), 0x101F));
}
__device__ __forceinline__ float swz16(float v) {  // lane ^= 16
    return __int_as_float(__builtin_amdgcn_ds_swizzle(__float_as_int(v), 0x401F));
}
// broadcast lane 0 of each 32-lane half (bbase = half-base byte address)
__device__ __forceinline__ float bperm0(float v, int bbase) {
    return __int_as_float(__builtin_amdgcn_ds_bpermute(bbase, __float_as_int(v)));
}

struct Sgn { float s1, s2, s4, s8, s16; };

// signed 32-point WHT; sign-FMA form v' = s_m*v + v[l^m], 2 issue-ops/stage,
// balanced across VALU (DPP) and DS (swizzle) pipes
__device__ __forceinline__ float wht32(float v, const Sgn& g) {
    v = fmaf(g.s1,  v, dppf<0xB1>(v));   // xor1  (VALU)
    v = fmaf(g.s2,  v, dppf<0x4E>(v));   // xor2  (VALU)
    v = fmaf(g.s4,  v, swz4(v));         // xor4  (DS)
    v = fmaf(g.s8,  v, dppf<0x128>(v));  // xor8  (VALU)
    v = fmaf(g.s16, v, swz16(v));        // xor16 (DS)
    return v;
}

// sum over each 32-lane half, result in every lane (rotations legal for sums)
__device__ __forceinline__ float sum32(float s) {
    s += dppf<0xB1>(s);    // xor1
    s += dppf<0x4E>(s);    // xor2
    s += dppf<0x124>(s);   // ror4 within 16
    s += dppf<0x128>(s);   // ror8 within 16
    s += swz16(s);         // xor16 (DS)
    return s;
}

__global__ __launch_bounds__(256, 8) void solver_kernel(
    const float* __restrict__ xg, const float* __restrict__ kg,
    const float* __restrict__ tg, float* __restrict__ out)
{
    const int tid = blockIdx.x * 256 + threadIdx.x;
    const int half = tid >> 5;                // [0, NPIX/ILP): 2 pixels/half
    const int lane = threadIdx.x & 63;
    const int l = lane & 31;                  // element = l-1; lane0 = WHT pad
    const int bbase = (lane & 32) << 2;

    const float t = tg[0];

    int pixi[ILP];
    pixi[0] = half;
    pixi[1] = half + NPIX / 2;

    float x[ILP], k[ILP];
#pragma unroll
    for (int j = 0; j < ILP; ++j) { x[j] = 1.0f; k[j] = 0.0f; }
    if (l >= 1) {
#pragma unroll
        for (int j = 0; j < ILP; ++j) {
            const int base = pixi[j] * NDIM + (l - 1);
            x[j] = xg[base];
            k[j] = kg[base];
        }
    }

    Sgn g;
    g.s1  = (l & 1)  ? -1.0f : 1.0f;
    g.s2  = (l & 2)  ? -1.0f : 1.0f;
    g.s4  = (l & 4)  ? -1.0f : 1.0f;
    g.s8  = (l & 8)  ? -1.0f : 1.0f;
    g.s16 = (l & 16) ? -1.0f : 1.0f;

    // per-pixel persistent state
    float w4[ILP], invx2[ILP], Minv[ILP];
    float r[ILP], z[ILP], p[ILP], rz[ILP], phi[ILP];

    // ---- setup: rate, v, w, b, Jacobi diag (two independent chains)
    {
        float xh[ILP], xh0[ILP], inv_rate[ILP], v[ILP], w[ILP];
#pragma unroll
        for (int j = 0; j < ILP; ++j) xh[j] = wht32(x[j], g);
#pragma unroll
        for (int j = 0; j < ILP; ++j) xh0[j] = bperm0(xh[j], bbase);
#pragma unroll
        for (int j = 0; j < ILP; ++j) {
            // rate = S x: 0.5*(T - WHT); lane-0 pad cancels algebraically
            float rate = 0.5f * (xh0[j] - xh[j]);
            inv_rate[j] = (l == 0) ? 0.0f : rcpf(rate);
            v[j] = t * (k[j] * inv_rate[j] - 1.0f) + inv_rate[j];
            w[j] = (t * k[j] + 1.0f) * inv_rate[j] * inv_rate[j];
        }
        float vh[ILP], wh[ILP];
#pragma unroll
        for (int j = 0; j < ILP; ++j) vh[j] = wht32(v[j], g);
#pragma unroll
        for (int j = 0; j < ILP; ++j) wh[j] = wht32(w[j], g);
#pragma unroll
        for (int j = 0; j < ILP; ++j) {
            float vh0 = bperm0(vh[j], bbase);
            float wh0 = bperm0(wh[j], bbase);
            float invx = rcpf(x[j]);
            invx2[j] = invx * invx;
            float b = -0.5f * (vh0 - vh[j]) - invx;
            if (l == 0) b = 0.0f;
            float dH = 0.5f * (wh0 - wh[j]) + invx2[j];
            Minv[j] = (l == 0) ? 0.0f : rcpf(dH);   // keeps lane0 state = 0
            w4[j] = 0.25f * w[j];   // folds both 0.5 transform scales
            r[j] = b;
            z[j] = Minv[j] * b;
            p[j] = z[j];
            phi[j] = 0.0f;
        }
#pragma unroll
        for (int j = 0; j < ILP; ++j) rz[j] = sum32(r[j] * z[j]);
    }

    // ---- PCG on H y = b; phi = b^T y accumulated as sum alpha_i * (r_i.z_i)
#pragma unroll
    for (int it = 0; it < CG_FULL; ++it) {
        float ph[ILP], q[ILP], qh[ILP], Ap[ILP], pAp[ILP];
#pragma unroll
        for (int j = 0; j < ILP; ++j) ph[j] = wht32(p[j], g);
#pragma unroll
        for (int j = 0; j < ILP; ++j) {
            float ph0 = bperm0(ph[j], bbase);
            q[j] = w4[j] * (ph0 - ph[j]);
        }
#pragma unroll
        for (int j = 0; j < ILP; ++j) qh[j] = wht32(q[j], g);
#pragma unroll
        for (int j = 0; j < ILP; ++j) {
            float qh0 = bperm0(qh[j], bbase);
            Ap[j] = fmaf(invx2[j], p[j], qh0 - qh[j]);
        }
#pragma unroll
        for (int j = 0; j < ILP; ++j) pAp[j] = sum32(p[j] * Ap[j]);
#pragma unroll
        for (int j = 0; j < ILP; ++j) {
            float alpha = rz[j] * rcpf(fmaxf(pAp[j], 1e-30f)); // no inf -> no NaN
            phi[j] = fmaf(alpha, rz[j], phi[j]);
            r[j] = fmaf(-alpha, Ap[j], r[j]);
            z[j] = Minv[j] * r[j];
        }
        float rzn[ILP];
#pragma unroll
        for (int j = 0; j < ILP; ++j) rzn[j] = sum32(r[j] * z[j]);
#pragma unroll
        for (int j = 0; j < ILP; ++j) {
            float beta = rzn[j] * rcpf(fmaxf(rz[j], 1e-30f));
            rz[j] = rzn[j];
            p[j] = fmaf(beta, p[j], z[j]);
        }
    }
    {   // final partial iteration: only the phi increment is observable
        float ph[ILP], q[ILP], qh[ILP], Ap[ILP], pAp[ILP];
#pragma unroll
        for (int j = 0; j < ILP; ++j) ph[j] = wht32(p[j], g);
#pragma unroll
        for (int j = 0; j < ILP; ++j) {
            float ph0 = bperm0(ph[j], bbase);
            q[j] = w4[j] * (ph0 - ph[j]);
        }
#pragma unroll
        for (int j = 0; j < ILP; ++j) qh[j] = wht32(q[j], g);
#pragma unroll
        for (int j = 0; j < ILP; ++j) {
            float qh0 = bperm0(qh[j], bbase);
            Ap[j] = fmaf(invx2[j], p[j], qh0 - qh[j]);
        }
#pragma unroll
        for (int j = 0; j < ILP; ++j) pAp[j] = sum32(p[j] * Ap[j]);
#pragma unroll
        for (int j = 0; j < ILP; ++j) {
            float alpha = rz[j] * rcpf(fmaxf(pAp[j], 1e-30f));
            phi[j] = fmaf(alpha, rz[j], phi[j]);
        }
    }

    if (l == 0) {
#pragma unroll
        for (int j = 0; j < ILP; ++j) out[pixi[j]] = phi[j];
    }
}

extern "C" void kernel_launch(void* const* d_in, const int* in_sizes, int n_in,
                              void* d_out, int out_size, void* d_ws, size_t ws_size,
                              hipStream_t stream) {
    const float* xg = (const float*)d_in[0];  // time_points
    const float* kg = (const float*)d_in[1];  // pixels
    // d_in[2] = S — Sylvester S-matrix, structure known analytically, unused
    const float* tg = (const float*)d_in[3];  // t scalar
    float* out = (float*)d_out;

    const int threads = 256;                  // 4 waves; 8 pixel-pairs per block
    const int blocks = (NPIX / ILP * 32) / threads; // 4096
    solver_kernel<<<blocks, threads, 0, stream>>>(xg, kg, tg, out);
}

// Round 4
// 75.471 us; speedup vs baseline: 1.1452x; 1.0445x over previous
//
#include <hip/hip_runtime.h>

#define NDIM 31
#define NPIX (256 * 256)
#define CG_FULL 3            // full CG iterations + 1 final partial (phi only)
#define TPB 256
#define BLK_DW (TPB * NDIM)  // 7936 dwords per array per block

__device__ __forceinline__ float rcpf(float x) { return __builtin_amdgcn_rcpf(x); }

// In-register 32-point Walsh-Hadamard transform. Fully unrolled, static
// indices only (rule: runtime-indexed arrays go to scratch). 160 add/sub,
// 16-wide ILP per stage, zero cross-lane traffic.
__device__ __forceinline__ void wht32r(float h[32]) {
#pragma unroll
    for (int s = 1; s < 32; s <<= 1) {
#pragma unroll
        for (int i = 0; i < 32; ++i) {
            if ((i & s) == 0) {
                const float a = h[i], b = h[i | s];
                h[i]     = a + b;
                h[i | s] = a - b;
            }
        }
    }
}

// One pixel per lane. The whole 31-vector lives in VGPRs; the S-multiply
// (rate = S x etc.) is a padded WHT with d[a] = h[0]-h[a+1] = 2*(S v)[a].
// Lane-0 broadcast of the old layout becomes the free register read h[0];
// dot products become in-lane fma chains (4-way split accumulators).
__global__ __launch_bounds__(TPB, 1) void solver_kernel(
    const float* __restrict__ xg, const float* __restrict__ kg,
    const float* __restrict__ tg, float* __restrict__ out)
{
    __shared__ float xs[BLK_DW];
    __shared__ float ks[BLK_DW];
    const int j = threadIdx.x;
    const int gbase = blockIdx.x * BLK_DW;

    // Coalesced stage: LDS mirrors the global slab verbatim (31 iters of
    // 1024B/wave loads). Per-lane reads below are stride-31 dwords: 31 is
    // odd -> all 32 banks distinct -> conflict-free.
#pragma unroll
    for (int i = 0; i < NDIM; ++i) {
        xs[i * TPB + j] = xg[gbase + i * TPB + j];
        ks[i * TPB + j] = kg[gbase + i * TPB + j];
    }
    __syncthreads();

    const float t = tg[0];
    const int lb = j * NDIM;

    float x[NDIM], k[NDIM];
#pragma unroll
    for (int i = 0; i < NDIM; ++i) { x[i] = xs[lb + i]; k[i] = ks[lb + i]; }

    // ---- rate = S x ; ir = 1/rate = 2/d
    float h[32];
    h[0] = 0.0f;                       // pad (coefficient cancels; 0 for safety)
#pragma unroll
    for (int i = 0; i < NDIM; ++i) h[i + 1] = x[i];
    wht32r(h);
    float ir[NDIM];
#pragma unroll
    for (int a = 0; a < NDIM; ++a) ir[a] = 2.0f * rcpf(h[0] - h[a + 1]);

    // ---- v (Jacobian vector) and w4 = w/4 (both WHT 0.5-scales folded in)
    float w4[NDIM];
    float hv[32], hw[32];
    hv[0] = 0.0f; hw[0] = 0.0f;
#pragma unroll
    for (int a = 0; a < NDIM; ++a) {
        const float ira = ir[a];
        hv[a + 1] = t * (k[a] * ira - 1.0f) + ira;
        const float wa = (t * k[a] + 1.0f) * ira * ira;
        hw[a + 1] = wa;
        w4[a] = 0.25f * wa;
    }
    wht32r(hv);
    wht32r(hw);

    // ---- b = J, Jacobi diag, CG init
    float invx2[NDIM], Minv[NDIM], r[NDIM], p[NDIM];
    float acc[4] = {0.f, 0.f, 0.f, 0.f};
#pragma unroll
    for (int i = 0; i < NDIM; ++i) {
        const float invx = rcpf(x[i]);
        invx2[i] = invx * invx;
        const float b  = -0.5f * (hv[0] - hv[i + 1]) - invx;
        const float dH =  0.5f * (hw[0] - hw[i + 1]) + invx2[i];
        Minv[i] = rcpf(dH);
        r[i] = b;
        const float z = Minv[i] * b;
        p[i] = z;
        acc[i & 3] = fmaf(b, z, acc[i & 3]);
    }
    float rz = (acc[0] + acc[1]) + (acc[2] + acc[3]);
    float phi = 0.0f;

    // ---- PCG on H y = b ; phi = sum alpha_i * (r_i . z_i)
#pragma unroll
    for (int it = 0; it < CG_FULL; ++it) {
        float hp[32];
        hp[0] = 0.0f;
#pragma unroll
        for (int i = 0; i < NDIM; ++i) hp[i + 1] = p[i];
        wht32r(hp);
        float hq[32];
        hq[0] = 0.0f;
#pragma unroll
        for (int a = 0; a < NDIM; ++a) hq[a + 1] = w4[a] * (hp[0] - hp[a + 1]);
        wht32r(hq);

        float Ap[NDIM];
        float pa[4] = {0.f, 0.f, 0.f, 0.f};
#pragma unroll
        for (int i = 0; i < NDIM; ++i) {
            Ap[i] = (hq[0] - hq[i + 1]) + invx2[i] * p[i];
            pa[i & 3] = fmaf(p[i], Ap[i], pa[i & 3]);
        }
        const float pAp = (pa[0] + pa[1]) + (pa[2] + pa[3]);
        const float alpha = rz * rcpf(fmaxf(pAp, 1e-30f)); // clamp: no inf->NaN
        phi = fmaf(alpha, rz, phi);

        float zbuf[NDIM];
        float ra[4] = {0.f, 0.f, 0.f, 0.f};
#pragma unroll
        for (int i = 0; i < NDIM; ++i) {
            r[i] = fmaf(-alpha, Ap[i], r[i]);
            const float z = Minv[i] * r[i];
            zbuf[i] = z;
            ra[i & 3] = fmaf(r[i], z, ra[i & 3]);
        }
        const float rzn = (ra[0] + ra[1]) + (ra[2] + ra[3]);
        const float beta = rzn * rcpf(fmaxf(rz, 1e-30f));
        rz = rzn;
#pragma unroll
        for (int i = 0; i < NDIM; ++i) p[i] = fmaf(beta, p[i], zbuf[i]);
    }

    {   // final partial iteration: p^T A p without forming Ap —
        // p^T A p = sum_a w4*(dp_a)^2 + sum_i invx2*p^2  (one WHT, not two)
        float hp[32];
        hp[0] = 0.0f;
#pragma unroll
        for (int i = 0; i < NDIM; ++i) hp[i + 1] = p[i];
        wht32r(hp);
        float pa[4] = {0.f, 0.f, 0.f, 0.f};
#pragma unroll
        for (int a = 0; a < NDIM; ++a) {
            const float d = hp[0] - hp[a + 1];
            pa[a & 3] = fmaf(w4[a] * d, d, pa[a & 3]);
            pa[a & 3] = fmaf(invx2[a] * p[a], p[a], pa[a & 3]);
        }
        const float pAp = (pa[0] + pa[1]) + (pa[2] + pa[3]);
        const float alpha = rz * rcpf(fmaxf(pAp, 1e-30f));
        phi = fmaf(alpha, rz, phi);
    }

    out[blockIdx.x * TPB + j] = phi;   // coalesced, every lane
}

extern "C" void kernel_launch(void* const* d_in, const int* in_sizes, int n_in,
                              void* d_out, int out_size, void* d_ws, size_t ws_size,
                              hipStream_t stream) {
    const float* xg = (const float*)d_in[0];  // time_points
    const float* kg = (const float*)d_in[1];  // pixels
    // d_in[2] = S — Sylvester S-matrix, structure known analytically, unused
    const float* tg = (const float*)d_in[3];  // t scalar
    float* out = (float*)d_out;

    const int blocks = NPIX / TPB;            // 256 blocks, 1 per CU
    solver_kernel<<<blocks, TPB, 0, stream>>>(xg, kg, tg, out);
}